// Round 1
// baseline (875.888 us; speedup 1.0000x reference)
//
#include <hip/hip_runtime.h>

#define B_ROWS 65536
#define DDIM   256
#define KEMB   1024
#define SOMX   32
#define SOMY   32
#define LRC    0.05f

#define BM 128
#define BN 128
#define KC 32

// ---------------- esq: per-embedding-row squared norm ----------------
__global__ __launch_bounds__(64) void esq_kernel(const float* __restrict__ E,
                                                 float* __restrict__ esq) {
  int k = blockIdx.x;
  int lane = threadIdx.x;              // 0..63, one float4 each (D=256)
  const float4 v = *(const float4*)(E + (size_t)k * DDIM + lane * 4);
  float s = v.x * v.x + v.y * v.y + v.z * v.z + v.w * v.w;
  for (int off = 32; off > 0; off >>= 1) s += __shfl_down(s, off, 64);
  if (lane == 0) esq[k] = s;
}

// ---------------- main: fused GEMM + argmin + epilogue ----------------
// dist(b,k) = |e_k|^2 - 2 x_b.e_k   (|x|^2 constant per row, dropped)
__global__ __launch_bounds__(256, 4) void main_kernel(
    const float* __restrict__ X, const float* __restrict__ E,
    const float* __restrict__ esq, float* __restrict__ S,
    double* __restrict__ sums, float* __restrict__ zq) {
  __shared__ __align__(16) float As[KC][BM + 4];
  __shared__ __align__(16) float Bs[KC][BN + 4];
  __shared__ float red_d[16][16];
  __shared__ int   red_i[16][16];
  __shared__ int   nmin_s[BM];
  __shared__ float fred[256];

  const int tid  = threadIdx.x;
  const int lane = tid & 63, wave = tid >> 6;
  // 8x8 lane grid per wave: A-reads and B-reads both 2-way-bank (free)
  const int tx = (lane & 7) | ((wave & 1) << 3);   // 0..15
  const int ty = (lane >> 3) | ((wave >> 1) << 3); // 0..15
  const int bm0 = blockIdx.x * BM;

  float rbest[8];
  int   ridx[8];
#pragma unroll
  for (int i = 0; i < 8; ++i) { rbest[i] = 3.4e38f; ridx[i] = 0; }

  for (int nt = 0; nt < KEMB / BN; ++nt) {
    float acc[8][8];
#pragma unroll
    for (int i = 0; i < 8; ++i)
#pragma unroll
      for (int j = 0; j < 8; ++j) acc[i][j] = 0.f;

    for (int kc = 0; kc < DDIM; kc += KC) {
      __syncthreads();
      // stage A(x rows) and B(e rows), transposed into k-major LDS
#pragma unroll
      for (int li = 0; li < 4; ++li) {
        int l = tid + 256 * li;          // 0..1023 float4 slots
        int m = l >> 3, kq = l & 7;      // m: tile row, kq: float4 along k
        float4 av = *(const float4*)(X + (size_t)(bm0 + m) * DDIM + kc + kq * 4);
        As[kq * 4 + 0][m] = av.x; As[kq * 4 + 1][m] = av.y;
        As[kq * 4 + 2][m] = av.z; As[kq * 4 + 3][m] = av.w;
        float4 bv = *(const float4*)(E + (size_t)(nt * BN + m) * DDIM + kc + kq * 4);
        Bs[kq * 4 + 0][m] = bv.x; Bs[kq * 4 + 1][m] = bv.y;
        Bs[kq * 4 + 2][m] = bv.z; Bs[kq * 4 + 3][m] = bv.w;
      }
      __syncthreads();
#pragma unroll 4
      for (int kk = 0; kk < KC; ++kk) {
        float4 a01 = *(const float4*)&As[kk][ty * 8];
        float4 a23 = *(const float4*)&As[kk][ty * 8 + 4];
        float4 b01 = *(const float4*)&Bs[kk][tx * 8];
        float4 b23 = *(const float4*)&Bs[kk][tx * 8 + 4];
        float a[8] = {a01.x, a01.y, a01.z, a01.w, a23.x, a23.y, a23.z, a23.w};
        float b[8] = {b01.x, b01.y, b01.z, b01.w, b23.x, b23.y, b23.z, b23.w};
#pragma unroll
        for (int i = 0; i < 8; ++i)
#pragma unroll
          for (int j = 0; j < 8; ++j) acc[i][j] += a[i] * b[j];
      }
    }
    // fold this n-tile into the running per-row argmin
#pragma unroll
    for (int j = 0; j < 8; ++j) {
      int col = nt * BN + tx * 8 + j;
      float eq = esq[col];
#pragma unroll
      for (int i = 0; i < 8; ++i) {
        float d = eq - 2.0f * acc[i][j];
        if (d < rbest[i]) { rbest[i] = d; ridx[i] = col; }
      }
    }
  }

  // cross-thread argmin per row (16 tx candidates per row)
  for (int i = 0; i < 8; ++i) {
    __syncthreads();
    red_d[ty][tx] = rbest[i];
    red_i[ty][tx] = ridx[i];
    __syncthreads();
    if (tx == 0) {
      float bd = red_d[ty][0]; int bi = red_i[ty][0];
      for (int t = 1; t < 16; ++t) {
        float d = red_d[ty][t]; int ii = red_i[ty][t];
        if (d < bd || (d == bd && ii < bi)) { bd = d; bi = ii; }
      }
      nmin_s[ty * 8 + i] = bi;
    }
  }
  __syncthreads();

  // ---------------- epilogue for this block's 128 rows ----------------
  float commit_p = 0.f, som_p = 0.f;
  for (int it = tid; it < BM * (DDIM / 4); it += 256) {
    int r  = it >> 6;        // row within block
    int c4 = it & 63;        // float4 column
    int k  = nmin_s[r];
    const float4 xv = *(const float4*)(X + (size_t)(bm0 + r) * DDIM + c4 * 4);
    const float4 ev = *(const float4*)(E + (size_t)k * DDIM + c4 * 4);
    *(float4*)(zq + (size_t)(bm0 + r) * DDIM + c4 * 4) = ev;
    float4 dw;
    dw.x = xv.x - ev.x; dw.y = xv.y - ev.y; dw.z = xv.z - ev.z; dw.w = xv.w - ev.w;
    float* Sp = S + (size_t)k * DDIM + c4 * 4;
    atomicAdd(Sp + 0, dw.x); atomicAdd(Sp + 1, dw.y);
    atomicAdd(Sp + 2, dw.z); atomicAdd(Sp + 3, dw.w);
    commit_p += dw.x * dw.x + dw.y * dw.y + dw.z * dw.z + dw.w * dw.w;
    int kx = k >> 5, ky = k & 31;
    int nb0 = (kx < SOMX - 1) ? k + SOMY : k;  // up
    int nb1 = (kx > 0)        ? k - SOMY : k;  // down
    int nb2 = (ky > 0)        ? k - 1    : k;  // left
    int nb3 = (ky < SOMY - 1) ? k + 1    : k;  // right
    int nb[4] = {nb0, nb1, nb2, nb3};
#pragma unroll
    for (int q = 0; q < 4; ++q) {
      const float4 en = *(const float4*)(E + (size_t)nb[q] * DDIM + c4 * 4);
      float d0 = xv.x - en.x, d1 = xv.y - en.y, d2 = xv.z - en.z, d3 = xv.w - en.w;
      som_p += d0 * d0 + d1 * d1 + d2 * d2 + d3 * d3;
    }
  }
  // block-reduce the two loss partials, one double atomic each
  fred[tid] = commit_p; __syncthreads();
  for (int s = 128; s > 0; s >>= 1) {
    if (tid < s) fred[tid] += fred[tid + s];
    __syncthreads();
  }
  if (tid == 0) atomicAdd(&sums[0], (double)fred[0]);
  __syncthreads();
  fred[tid] = som_p; __syncthreads();
  for (int s = 128; s > 0; s >>= 1) {
    if (tid < s) fred[tid] += fred[tid + s];
    __syncthreads();
  }
  if (tid == 0) atomicAdd(&sums[1], (double)fred[0]);
}

// ---------------- stencil: new_embeddings + scalar losses ----------------
// seg(idx_up)[k] = sum_{j: f_up(j)=k} S[j]; inverse of the clamped maps:
//   up-slot:    kx>=1 ? S[k-32] : S[k]
//   down-slot:  kx<=30 ? S[k+32] : S[k]
//   left-slot:  ky>=1 ? S[k-1]  : S[k]
//   right-slot: ky<=30 ? S[k+1] : S[k]
__global__ __launch_bounds__(256) void stencil_kernel(
    const float* __restrict__ E, const float* __restrict__ S,
    const double* __restrict__ sums, float* __restrict__ out) {
  int idx = blockIdx.x * 256 + threadIdx.x;   // 0 .. K*D-1
  int k = idx >> 8;      // D = 256
  int c = idx & 255;
  int kx = k >> 5, ky = k & 31;
  int j1 = (kx >= 1)        ? k - SOMY : k;
  int j2 = (kx <= SOMX - 2) ? k + SOMY : k;
  int j3 = (ky >= 1)        ? k - 1    : k;
  int j4 = (ky <= SOMY - 2) ? k + 1    : k;
  float v = E[idx] + LRC * S[idx] +
            0.5f * LRC * (S[(size_t)j1 * DDIM + c] + S[(size_t)j2 * DDIM + c] +
                          S[(size_t)j3 * DDIM + c] + S[(size_t)j4 * DDIM + c]);
  out[(size_t)B_ROWS * DDIM + 2 + idx] = v;
  if (idx == 0) {
    out[(size_t)B_ROWS * DDIM]     = (float)(sums[0] / ((double)B_ROWS * DDIM));
    out[(size_t)B_ROWS * DDIM + 1] = (float)(sums[1] / ((double)B_ROWS * 4.0 * DDIM));
  }
}

extern "C" void kernel_launch(void* const* d_in, const int* in_sizes, int n_in,
                              void* d_out, int out_size, void* d_ws, size_t ws_size,
                              hipStream_t stream) {
  const float* X = (const float*)d_in[0];
  const float* E = (const float*)d_in[1];
  float* out = (float*)d_out;
  char* ws = (char*)d_ws;
  float*  S    = (float*)ws;                                   // K*D fp32 = 1 MB
  double* sums = (double*)(ws + (size_t)KEMB * DDIM * 4);      // 2 doubles
  float*  esq  = (float*)(ws + (size_t)KEMB * DDIM * 4 + 16);  // K fp32

  hipMemsetAsync(ws, 0, (size_t)KEMB * DDIM * 4 + 16, stream);
  esq_kernel<<<KEMB, 64, 0, stream>>>(E, esq);
  main_kernel<<<B_ROWS / BM, 256, 0, stream>>>(X, E, esq, S, sums, out);
  stencil_kernel<<<KEMB * DDIM / 256, 256, 0, stream>>>(E, S, sums, out);
}

// Round 2
// 712.804 us; speedup vs baseline: 1.2288x; 1.2288x over previous
//
#include <hip/hip_runtime.h>

#define B_ROWS 65536
#define DDIM   256
#define KEMB   1024
#define SOMX   32
#define SOMY   32
#define LRC    0.05f

#define BM 128
#define BN 128
#define KC 32

typedef __attribute__((ext_vector_type(8))) short short8;
typedef __attribute__((ext_vector_type(4))) float f32x4;

static __device__ __forceinline__ unsigned short f2bf(float f) {
  unsigned int u = __float_as_uint(f);
  u += 0x7fffu + ((u >> 16) & 1u);
  return (unsigned short)(u >> 16);
}
static __device__ __forceinline__ float bf2f(unsigned short h) {
  return __uint_as_float(((unsigned int)h) << 16);
}

// ---------------- esq: per-embedding-row squared norm (fp32 exact) ----------------
__global__ __launch_bounds__(64) void esq_kernel(const float* __restrict__ E,
                                                 float* __restrict__ esq) {
  int k = blockIdx.x;
  int lane = threadIdx.x;
  const float4 v = *(const float4*)(E + (size_t)k * DDIM + lane * 4);
  float s = v.x * v.x + v.y * v.y + v.z * v.z + v.w * v.w;
  for (int off = 32; off > 0; off >>= 1) s += __shfl_down(s, off, 64);
  if (lane == 0) esq[k] = s;
}

// ---------------- convert: X -> hi/lo bf16 interleaved into out region; E -> ws ----
// out region layout per x-row: [256 bf16 hi | 256 bf16 lo] = 1024 B = one zq row.
__global__ __launch_bounds__(256) void convert_kernel(
    const float* __restrict__ X, const float* __restrict__ E,
    unsigned short* __restrict__ outU,
    unsigned short* __restrict__ Eh, unsigned short* __restrict__ El) {
  const size_t nX8 = (size_t)B_ROWS * DDIM / 8;
  size_t i = (size_t)blockIdx.x * 256 + threadIdx.x;
  const float* src;
  unsigned short *dh, *dl;
  size_t off;
  if (i < nX8) {
    off = i * 8;
    size_t r = off >> 8, c = off & 255;
    src = X;
    dh = outU + r * 512 + c;
    dl = dh + 256;
  } else {
    off = (i - nX8) * 8;
    src = E;
    dh = Eh + off;
    dl = El + off;
    off = off; // E offset
  }
  const float4 v0 = *(const float4*)(src + ((i < nX8) ? i * 8 : (i - nX8) * 8));
  const float4 v1 = *(const float4*)(src + ((i < nX8) ? i * 8 : (i - nX8) * 8) + 4);
  float f[8] = {v0.x, v0.y, v0.z, v0.w, v1.x, v1.y, v1.z, v1.w};
  unsigned short h[8], l[8];
#pragma unroll
  for (int j = 0; j < 8; ++j) {
    h[j] = f2bf(f[j]);
    float r = f[j] - bf2f(h[j]);
    l[j] = f2bf(r);
  }
  *(uint4*)dh = *(const uint4*)h;
  *(uint4*)dl = *(const uint4*)l;
}

// ---------------- main: MFMA dist-GEMM + argmin + fused epilogue ----------------
// dist(b,k) = esq[k] - 2 x_b.e_k ; dot via bf16 split: xh.eh + xh.el + xl.eh
__global__ __launch_bounds__(256, 3) void main_kernel(
    const unsigned short* __restrict__ XhlU,   // = out region (hi/lo interleaved)
    const unsigned short* __restrict__ EhW, const unsigned short* __restrict__ ElW,
    const float* __restrict__ X, const float* __restrict__ E,
    const float* __restrict__ esq, float* __restrict__ S,
    double* __restrict__ sums, float* __restrict__ zq) {
  __shared__ __align__(16) unsigned short sT[4][BM][KC + 8];  // Xh,Xl,Eh,El tiles
  __shared__ float cdd[2][BM];
  __shared__ int   cdi[2][BM];
  __shared__ int   nmin_s[BM];
  __shared__ float fred[256];

  const int tid  = threadIdx.x;
  const int lane = tid & 63, w = tid >> 6;
  const int lrow = lane & 15;            // MFMA frag row (A) / col (B)
  const int koff = (lane >> 4) * 8;      // MFMA frag k offset
  const int rowbase = (w >> 1) * 64;     // wave's 64-row sector
  const int colb    = (w & 1) * 64;      // wave's 64-col sector
  const int bm0 = blockIdx.x * BM;
  const int s4 = tid & 3;

  float rbest[16];
  int   ridx[16];
#pragma unroll
  for (int i = 0; i < 16; ++i) { rbest[i] = 3.4e38f; ridx[i] = 0; }

  for (int nt = 0; nt < KEMB / BN; ++nt) {
    f32x4 acc[4][4];
#pragma unroll
    for (int i = 0; i < 4; ++i)
#pragma unroll
      for (int j = 0; j < 4; ++j) acc[i][j] = (f32x4){0.f, 0.f, 0.f, 0.f};

    const unsigned short* srcs[4];
    srcs[0] = XhlU + (size_t)bm0 * 512;          // X hi (row stride 512)
    srcs[1] = XhlU + (size_t)bm0 * 512 + 256;    // X lo
    srcs[2] = EhW + (size_t)nt * BN * DDIM;      // E hi (row stride 256)
    srcs[3] = ElW + (size_t)nt * BN * DDIM;      // E lo

    for (int kc = 0; kc < DDIM; kc += KC) {
      __syncthreads();
      // stage 4 tiles of [128][32] bf16; tile = i>>1, 64 rows per i
#pragma unroll
      for (int i = 0; i < 8; ++i) {
        const int tile = i >> 1;
        const int stride = (tile < 2) ? 512 : 256;
        const int row = ((i & 1) << 6) + (tid >> 2);
        const uint4 v = *(const uint4*)(srcs[tile] + (size_t)row * stride + kc + s4 * 8);
        *(uint4*)&sT[tile][row][s4 * 8] = v;
      }
      __syncthreads();
      // 3 term-passes: (Xh,Eh), (Xh,El), (Xl,Eh)
#pragma unroll
      for (int p = 0; p < 3; ++p) {
        const int at = (p < 2) ? 0 : 1;
        const int bt = (p == 1) ? 3 : 2;
        short8 af[4], bfr[4];
#pragma unroll
        for (int t = 0; t < 4; ++t) {
          af[t]  = *(const short8*)&sT[at][rowbase + t * 16 + lrow][koff];
          bfr[t] = *(const short8*)&sT[bt][colb    + t * 16 + lrow][koff];
        }
#pragma unroll
        for (int tr = 0; tr < 4; ++tr)
#pragma unroll
          for (int tc = 0; tc < 4; ++tc)
            acc[tr][tc] = __builtin_amdgcn_mfma_f32_16x16x32_bf16(
                af[tr], bfr[tc], acc[tr][tc], 0, 0, 0);
      }
    }
    // fold this n-tile into per-row argmin state
#pragma unroll
    for (int tc = 0; tc < 4; ++tc) {
      const int col = nt * BN + colb + tc * 16 + lrow;
      const float eq = esq[col];
#pragma unroll
      for (int tr = 0; tr < 4; ++tr)
#pragma unroll
        for (int r = 0; r < 4; ++r) {
          float d = eq - 2.0f * acc[tr][tc][r];
          const int slot = tr * 4 + r;
          if (d < rbest[slot]) { rbest[slot] = d; ridx[slot] = col; }
        }
    }
  }

  // cross-lane argmin: 16 candidates per row live in the 16-lane col group
#pragma unroll
  for (int slot = 0; slot < 16; ++slot) {
    float bd = rbest[slot];
    int   bi = ridx[slot];
#pragma unroll
    for (int off = 1; off < 16; off <<= 1) {
      float od = __shfl_xor(bd, off, 64);
      int   oi = __shfl_xor(bi, off, 64);
      if (od < bd || (od == bd && oi < bi)) { bd = od; bi = oi; }
    }
    if (lrow == 0) {
      const int row = rowbase + (slot >> 2) * 16 + (lane >> 4) * 4 + (slot & 3);
      cdd[w & 1][row] = bd;
      cdi[w & 1][row] = bi;
    }
  }
  __syncthreads();
  if (tid < BM) {
    float d0 = cdd[0][tid], d1 = cdd[1][tid];
    int   i0 = cdi[0][tid], i1 = cdi[1][tid];
    nmin_s[tid] = (d1 < d0 || (d1 == d0 && i1 < i0)) ? i1 : i0;
  }
  __syncthreads();

  // ---------------- epilogue: zq write (overwrites hi/lo), scatter, losses ---------
  float commit_p = 0.f, som_p = 0.f;
  for (int it = tid; it < BM * (DDIM / 4); it += 256) {
    int r  = it >> 6;
    int c4 = it & 63;
    int k  = nmin_s[r];
    const float4 xv = *(const float4*)(X + (size_t)(bm0 + r) * DDIM + c4 * 4);
    const float4 ev = *(const float4*)(E + (size_t)k * DDIM + c4 * 4);
    *(float4*)(zq + (size_t)(bm0 + r) * DDIM + c4 * 4) = ev;
    float4 dw;
    dw.x = xv.x - ev.x; dw.y = xv.y - ev.y; dw.z = xv.z - ev.z; dw.w = xv.w - ev.w;
    float* Sp = S + (size_t)k * DDIM + c4 * 4;
    atomicAdd(Sp + 0, dw.x); atomicAdd(Sp + 1, dw.y);
    atomicAdd(Sp + 2, dw.z); atomicAdd(Sp + 3, dw.w);
    commit_p += dw.x * dw.x + dw.y * dw.y + dw.z * dw.z + dw.w * dw.w;
    int kx = k >> 5, ky = k & 31;
    int nb[4];
    nb[0] = (kx < SOMX - 1) ? k + SOMY : k;
    nb[1] = (kx > 0)        ? k - SOMY : k;
    nb[2] = (ky > 0)        ? k - 1    : k;
    nb[3] = (ky < SOMY - 1) ? k + 1    : k;
#pragma unroll
    for (int q = 0; q < 4; ++q) {
      const float4 en = *(const float4*)(E + (size_t)nb[q] * DDIM + c4 * 4);
      float d0 = xv.x - en.x, d1 = xv.y - en.y, d2 = xv.z - en.z, d3 = xv.w - en.w;
      som_p += d0 * d0 + d1 * d1 + d2 * d2 + d3 * d3;
    }
  }
  fred[tid] = commit_p; __syncthreads();
  for (int s = 128; s > 0; s >>= 1) {
    if (tid < s) fred[tid] += fred[tid + s];
    __syncthreads();
  }
  if (tid == 0) atomicAdd(&sums[0], (double)fred[0]);
  __syncthreads();
  fred[tid] = som_p; __syncthreads();
  for (int s = 128; s > 0; s >>= 1) {
    if (tid < s) fred[tid] += fred[tid + s];
    __syncthreads();
  }
  if (tid == 0) atomicAdd(&sums[1], (double)fred[0]);
}

// ---------------- stencil: new_embeddings + scalar losses ----------------
__global__ __launch_bounds__(256) void stencil_kernel(
    const float* __restrict__ E, const float* __restrict__ S,
    const double* __restrict__ sums, float* __restrict__ out) {
  int idx = blockIdx.x * 256 + threadIdx.x;
  int k = idx >> 8;
  int c = idx & 255;
  int kx = k >> 5, ky = k & 31;
  int j1 = (kx >= 1)        ? k - SOMY : k;
  int j2 = (kx <= SOMX - 2) ? k + SOMY : k;
  int j3 = (ky >= 1)        ? k - 1    : k;
  int j4 = (ky <= SOMY - 2) ? k + 1    : k;
  float v = E[idx] + LRC * S[idx] +
            0.5f * LRC * (S[(size_t)j1 * DDIM + c] + S[(size_t)j2 * DDIM + c] +
                          S[(size_t)j3 * DDIM + c] + S[(size_t)j4 * DDIM + c]);
  out[(size_t)B_ROWS * DDIM + 2 + idx] = v;
  if (idx == 0) {
    out[(size_t)B_ROWS * DDIM]     = (float)(sums[0] / ((double)B_ROWS * DDIM));
    out[(size_t)B_ROWS * DDIM + 1] = (float)(sums[1] / ((double)B_ROWS * 4.0 * DDIM));
  }
}

extern "C" void kernel_launch(void* const* d_in, const int* in_sizes, int n_in,
                              void* d_out, int out_size, void* d_ws, size_t ws_size,
                              hipStream_t stream) {
  const float* X = (const float*)d_in[0];
  const float* E = (const float*)d_in[1];
  float* out = (float*)d_out;
  unsigned short* outU = (unsigned short*)d_out;
  char* ws = (char*)d_ws;

  float*          S    = (float*)ws;                          // 1 MB
  double*         sums = (double*)(ws + 1048576);             // 16 B
  float*          esq  = (float*)(ws + 1048592);              // 4 KB
  unsigned short* EhW  = (unsigned short*)(ws + 1052688);     // 512 KB
  unsigned short* ElW  = (unsigned short*)(ws + 1052688 + 524288);

  hipMemsetAsync(ws, 0, 1048592, stream);
  convert_kernel<<<(B_ROWS * (DDIM / 8) + KEMB * (DDIM / 8)) / 256, 256, 0, stream>>>(
      X, E, outU, EhW, ElW);
  esq_kernel<<<KEMB, 64, 0, stream>>>(E, esq);
  main_kernel<<<B_ROWS / BM, 256, 0, stream>>>(outU, EhW, ElW, X, E, esq, S, sums, out);
  stencil_kernel<<<KEMB * DDIM / 256, 256, 0, stream>>>(E, S, sums, out);
}

// Round 3
// 524.645 us; speedup vs baseline: 1.6695x; 1.3586x over previous
//
#include <hip/hip_runtime.h>

#define B_ROWS 65536
#define DDIM   256
#define KEMB   1024
#define LRC    0.05f
#define BM 128
#define BN 128
#define KC 32

typedef __attribute__((ext_vector_type(8))) short short8;
typedef __attribute__((ext_vector_type(4))) float f32x4;

// ---- workspace layout (bytes) ----
#define SX_OFF    0u            // 1 MB fp32 [K][D]
#define CNT_OFF   1048576u      // 4 KB int [K]
#define SUMS_OFF  1052672u      // 32 B, 4 doubles
#define ESQ_OFF   1052704u      // 4 KB fp32 [K]
#define CUR_OFF   1056800u      // 4 KB int [K]
#define NMIN_OFF  1060896u      // 512 KB u64 [B]
#define ROWS_OFF  1585184u      // 256 KB int [B]
#define EH_OFF    1847328u      // 512 KB bf16 [K][D]
#define EL_OFF    2371616u      // 512 KB

static __device__ __forceinline__ unsigned short f2bf(float f) {
  unsigned int u = __float_as_uint(f);
  u += 0x7fffu + ((u >> 16) & 1u);
  return (unsigned short)(u >> 16);
}
static __device__ __forceinline__ float bf2f(unsigned short h) {
  return __uint_as_float(((unsigned int)h) << 16);
}
static __device__ __forceinline__ int nmin_of(const unsigned long long* nm, int b) {
  return (int)(nm[b] & 0xffffffffull);
}

// ---------------- esq ----------------
__global__ __launch_bounds__(64) void esq_kernel(const float* __restrict__ E,
                                                 float* __restrict__ esq) {
  int k = blockIdx.x, lane = threadIdx.x;
  const float4 v = *(const float4*)(E + (size_t)k * DDIM + lane * 4);
  float s = v.x * v.x + v.y * v.y + v.z * v.z + v.w * v.w;
  for (int off = 32; off > 0; off >>= 1) s += __shfl_down(s, off, 64);
  if (lane == 0) esq[k] = s;
}

// ---------------- convert: X->hi/lo into out region; E->ws; Sum|x|^2 ----------------
__global__ __launch_bounds__(256) void convert_kernel(
    const float* __restrict__ X, const float* __restrict__ E,
    unsigned short* __restrict__ outU,
    unsigned short* __restrict__ Eh, unsigned short* __restrict__ El,
    double* __restrict__ sums) {
  __shared__ float red[256];
  const size_t nX8 = (size_t)B_ROWS * DDIM / 8;
  size_t i = (size_t)blockIdx.x * 256 + threadIdx.x;
  const float* src;
  unsigned short *dh, *dl;
  bool isX = (i < nX8);
  if (isX) {
    size_t off = i * 8;
    src = X + off;
    dh = outU + (off >> 8) * 512 + (off & 255);
    dl = dh + 256;
  } else {
    size_t off = (i - nX8) * 8;
    src = E + off;
    dh = Eh + off;
    dl = El + off;
  }
  const float4 v0 = *(const float4*)src;
  const float4 v1 = *(const float4*)(src + 4);
  float f[8] = {v0.x, v0.y, v0.z, v0.w, v1.x, v1.y, v1.z, v1.w};
  unsigned short h[8], l[8];
  float part = 0.f;
#pragma unroll
  for (int j = 0; j < 8; ++j) {
    h[j] = f2bf(f[j]);
    l[j] = f2bf(f[j] - bf2f(h[j]));
    part += f[j] * f[j];
  }
  *(uint4*)dh = *(const uint4*)h;
  *(uint4*)dl = *(const uint4*)l;
  red[threadIdx.x] = isX ? part : 0.f;
  __syncthreads();
  for (int s = 128; s > 0; s >>= 1) {
    if (threadIdx.x < s) red[threadIdx.x] += red[threadIdx.x + s];
    __syncthreads();
  }
  if (threadIdx.x == 0) atomicAdd(&sums[0], (double)red[0]);
}

// ---------------- A: MFMA dist-GEMM + argmin -> packed atomicMin ----------------
__global__ __launch_bounds__(256, 4) void gemm_argmin_kernel(
    const unsigned short* __restrict__ XhlU,
    const unsigned short* __restrict__ EhW, const unsigned short* __restrict__ ElW,
    const float* __restrict__ esq, unsigned long long* __restrict__ nmin64) {
  __shared__ __align__(16) unsigned short sT[4][BM][KC + 8];  // 40960 B exactly

  const int tid  = threadIdx.x;
  const int lane = tid & 63, w = tid >> 6;
  const int lrow = lane & 15;
  const int koff = (lane >> 4) * 8;
  const int rowbase = (w >> 1) * 64;
  const int colb    = (w & 1) * 64;
  const int bm0 = (int)(blockIdx.x >> 1) * BM;
  const int ntbase = (int)(blockIdx.x & 1) * 4;
  const int s4 = tid & 3;

  float rbest[16];
  int   ridx[16];
#pragma unroll
  for (int i = 0; i < 16; ++i) { rbest[i] = 3.4e38f; ridx[i] = 0; }

  for (int ntl = 0; ntl < 4; ++ntl) {
    const int nt = ntbase + ntl;
    f32x4 acc[4][4];
#pragma unroll
    for (int i = 0; i < 4; ++i)
#pragma unroll
      for (int j = 0; j < 4; ++j) acc[i][j] = (f32x4){0.f, 0.f, 0.f, 0.f};

    const unsigned short* srcs[4];
    srcs[0] = XhlU + (size_t)bm0 * 512;
    srcs[1] = XhlU + (size_t)bm0 * 512 + 256;
    srcs[2] = EhW + (size_t)nt * BN * DDIM;
    srcs[3] = ElW + (size_t)nt * BN * DDIM;

    for (int kc = 0; kc < DDIM; kc += KC) {
      __syncthreads();
#pragma unroll
      for (int i = 0; i < 8; ++i) {
        const int tile = i >> 1;
        const int stride = (tile < 2) ? 512 : 256;
        const int row = ((i & 1) << 6) + (tid >> 2);
        const uint4 v = *(const uint4*)(srcs[tile] + (size_t)row * stride + kc + s4 * 8);
        *(uint4*)&sT[tile][row][s4 * 8] = v;
      }
      __syncthreads();
#pragma unroll
      for (int p = 0; p < 3; ++p) {
        const int at = (p < 2) ? 0 : 1;
        const int bt = (p == 1) ? 3 : 2;
        short8 af[4], bfr[4];
#pragma unroll
        for (int t = 0; t < 4; ++t) {
          af[t]  = *(const short8*)&sT[at][rowbase + t * 16 + lrow][koff];
          bfr[t] = *(const short8*)&sT[bt][colb    + t * 16 + lrow][koff];
        }
#pragma unroll
        for (int tr = 0; tr < 4; ++tr)
#pragma unroll
          for (int tc = 0; tc < 4; ++tc)
            acc[tr][tc] = __builtin_amdgcn_mfma_f32_16x16x32_bf16(
                af[tr], bfr[tc], acc[tr][tc], 0, 0, 0);
      }
    }
#pragma unroll
    for (int tc = 0; tc < 4; ++tc) {
      const int col = nt * BN + colb + tc * 16 + lrow;
      const float eq = esq[col];
#pragma unroll
      for (int tr = 0; tr < 4; ++tr)
#pragma unroll
        for (int r = 0; r < 4; ++r) {
          float d = eq - 2.0f * acc[tr][tc][r];
          const int slot = tr * 4 + r;
          if (d < rbest[slot]) { rbest[slot] = d; ridx[slot] = col; }
        }
    }
  }

  __syncthreads();  // done with sT as tiles; reuse as reduction scratch
  float* cdd = (float*)&sT[0][0][0];      // [2][128]
  int*   cdi = (int*)(cdd + 256);         // [2][128]

#pragma unroll
  for (int slot = 0; slot < 16; ++slot) {
    float bd = rbest[slot];
    int   bi = ridx[slot];
#pragma unroll
    for (int off = 1; off < 16; off <<= 1) {
      float od = __shfl_xor(bd, off, 64);
      int   oi = __shfl_xor(bi, off, 64);
      if (od < bd || (od == bd && oi < bi)) { bd = od; bi = oi; }
    }
    if (lrow == 0) {
      const int row = rowbase + (slot >> 2) * 16 + (lane >> 4) * 4 + (slot & 3);
      cdd[(w & 1) * 128 + row] = bd;
      cdi[(w & 1) * 128 + row] = bi;
    }
  }
  __syncthreads();
  if (tid < BM) {
    float d0 = cdd[tid], d1 = cdd[128 + tid];
    int   i0 = cdi[tid], i1 = cdi[128 + tid];
    float bd = d0; int bi = i0;
    if (d1 < d0 || (d1 == d0 && i1 < i0)) { bd = d1; bi = i1; }
    unsigned int fb = __float_as_uint(bd);
    fb = (fb & 0x80000000u) ? ~fb : (fb | 0x80000000u);
    unsigned long long key = ((unsigned long long)fb << 32) | (unsigned int)bi;
    atomicMin(&nmin64[bm0 + tid], key);
  }
}

// ---------------- zq gather ----------------
__global__ __launch_bounds__(256) void zq_kernel(
    const unsigned long long* __restrict__ nm, const float* __restrict__ E,
    float* __restrict__ zq) {
  int row = blockIdx.x * 4 + (threadIdx.x >> 6);
  int lane = threadIdx.x & 63;
  int k = nmin_of(nm, row);
  const float4 v = *(const float4*)(E + (size_t)k * DDIM + lane * 4);
  *(float4*)(zq + (size_t)row * DDIM + lane * 4) = v;
}

// ---------------- hist ----------------
__global__ __launch_bounds__(1024) void hist_kernel(
    const unsigned long long* __restrict__ nm, int* __restrict__ counts) {
  __shared__ int h[KEMB];
  int tid = threadIdx.x;
  h[tid] = 0;
  __syncthreads();
  int k = nmin_of(nm, blockIdx.x * 1024 + tid);
  atomicAdd(&h[k], 1);
  __syncthreads();
  if (h[tid] > 0) atomicAdd(&counts[tid], h[tid]);
}

// ---------------- scan: exclusive prefix of counts -> cur ----------------
__global__ __launch_bounds__(1024) void scan_kernel(
    const int* __restrict__ counts, int* __restrict__ cur) {
  __shared__ int tmp[KEMB];
  int tid = threadIdx.x;
  int v = counts[tid];
  tmp[tid] = v;
  __syncthreads();
  for (int off = 1; off < 1024; off <<= 1) {
    int u = (tid >= off) ? tmp[tid - off] : 0;
    __syncthreads();
    tmp[tid] += u;
    __syncthreads();
  }
  cur[tid] = tmp[tid] - v;
}

// ---------------- scatter: stable-ish counting-sort of row ids by k ----------------
__global__ __launch_bounds__(1024) void scatter_kernel(
    const unsigned long long* __restrict__ nm, int* __restrict__ cur,
    int* __restrict__ rows) {
  __shared__ int lcnt[KEMB], lbase[KEMB], lrank[KEMB];
  int tid = threadIdx.x;
  lcnt[tid] = 0; lrank[tid] = 0;
  __syncthreads();
  int b = blockIdx.x * 1024 + tid;
  int k = nmin_of(nm, b);
  atomicAdd(&lcnt[k], 1);
  __syncthreads();
  if (lcnt[tid] > 0) lbase[tid] = atomicAdd(&cur[tid], lcnt[tid]);
  __syncthreads();
  int r = atomicAdd(&lrank[k], 1);
  rows[lbase[k] + r] = b;
}

// ---------------- sxsum: segment-sum sorted chunks into SX ----------------
__global__ __launch_bounds__(256) void sxsum_kernel(
    const int* __restrict__ rows, const unsigned long long* __restrict__ nm,
    const float* __restrict__ X, float* __restrict__ SX) {
  __shared__ int sb[64], sk[64];
  int tid = threadIdx.x;
  int p0 = blockIdx.x * 64;
  if (tid < 64) sb[tid] = rows[p0 + tid];
  __syncthreads();
  if (tid < 64) sk[tid] = nmin_of(nm, sb[tid]);
  __syncthreads();
  float acc = 0.f;
  int kprev = sk[0];
  for (int i = 0; i < 64; ++i) {
    int k = sk[i];
    if (k != kprev) {
      atomicAdd(&SX[(size_t)kprev * DDIM + tid], acc);
      acc = 0.f;
      kprev = k;
    }
    acc += X[(size_t)sb[i] * DDIM + tid];
  }
  atomicAdd(&SX[(size_t)kprev * DDIM + tid], acc);
}

// ---------------- stencil: new_embeddings + loss partials ----------------
// seg[j] = SX[j] - c_j*E[j]; new_emb[k] = E[k] + LR*seg[k] + 0.5LR*(4 backward taps)
__global__ __launch_bounds__(256) void stencil_kernel(
    const float* __restrict__ E, const float* __restrict__ SX,
    const int* __restrict__ counts, const float* __restrict__ esq,
    double* __restrict__ sums, float* __restrict__ out) {
  __shared__ float redc[256], reds[256];
  int k = blockIdx.x, t = threadIdx.x;
  int kx = k >> 5, ky = k & 31;
  // backward taps (boundary self-terms cancel pairwise; round-1-verified form)
  int j1 = (kx >= 1)  ? k - 32 : k;
  int j2 = (kx <= 30) ? k + 32 : k;
  int j3 = (ky >= 1)  ? k - 1  : k;
  int j4 = (ky <= 30) ? k + 1  : k;
  // forward neighbors (for som loss)
  int fU = (kx < 31) ? k + 32 : k;
  int fD = (kx > 0)  ? k - 32 : k;
  int fL = (ky > 0)  ? k - 1  : k;
  int fR = (ky < 31) ? k + 1  : k;

  float e   = E[(size_t)k * DDIM + t];
  float sxk = SX[(size_t)k * DDIM + t];
  float Tk = sxk - (float)counts[k] * e;
  float T1 = SX[(size_t)j1 * DDIM + t] - (float)counts[j1] * E[(size_t)j1 * DDIM + t];
  float T2 = SX[(size_t)j2 * DDIM + t] - (float)counts[j2] * E[(size_t)j2 * DDIM + t];
  float T3 = SX[(size_t)j3 * DDIM + t] - (float)counts[j3] * E[(size_t)j3 * DDIM + t];
  float T4 = SX[(size_t)j4 * DDIM + t] - (float)counts[j4] * E[(size_t)j4 * DDIM + t];
  float v = e + LRC * Tk + 0.5f * LRC * (T1 + T2 + T3 + T4);
  out[(size_t)B_ROWS * DDIM + 2 + (size_t)k * DDIM + t] = v;

  float eU = E[(size_t)fU * DDIM + t], eD = E[(size_t)fD * DDIM + t];
  float eL = E[(size_t)fL * DDIM + t], eR = E[(size_t)fR * DDIM + t];
  float cp = -2.f * sxk * e;
  float sp = -2.f * sxk * (eU + eD + eL + eR);
  if (t == 0) {
    float ck = (float)counts[k];
    cp += ck * esq[k];
    sp += ck * (esq[fU] + esq[fD] + esq[fL] + esq[fR]);
  }
  redc[t] = cp; reds[t] = sp;
  __syncthreads();
  for (int s = 128; s > 0; s >>= 1) {
    if (t < s) { redc[t] += redc[t + s]; reds[t] += reds[t + s]; }
    __syncthreads();
  }
  if (t == 0) {
    atomicAdd(&sums[1], (double)redc[0]);
    atomicAdd(&sums[2], (double)reds[0]);
  }
}

// ---------------- finalize losses ----------------
__global__ void finalize_kernel(const double* __restrict__ sums,
                                float* __restrict__ out) {
  double xsq = sums[0];
  out[(size_t)B_ROWS * DDIM]     = (float)((xsq + sums[1]) / ((double)B_ROWS * DDIM));
  out[(size_t)B_ROWS * DDIM + 1] =
      (float)((4.0 * xsq + sums[2]) / ((double)B_ROWS * 4.0 * DDIM));
}

extern "C" void kernel_launch(void* const* d_in, const int* in_sizes, int n_in,
                              void* d_out, int out_size, void* d_ws, size_t ws_size,
                              hipStream_t stream) {
  const float* X = (const float*)d_in[0];
  const float* E = (const float*)d_in[1];
  float* out = (float*)d_out;
  unsigned short* outU = (unsigned short*)d_out;
  char* ws = (char*)d_ws;

  float*              SX    = (float*)(ws + SX_OFF);
  int*                cnts  = (int*)(ws + CNT_OFF);
  double*             sums  = (double*)(ws + SUMS_OFF);
  float*              esq   = (float*)(ws + ESQ_OFF);
  int*                cur   = (int*)(ws + CUR_OFF);
  unsigned long long* nm64  = (unsigned long long*)(ws + NMIN_OFF);
  int*                rows  = (int*)(ws + ROWS_OFF);
  unsigned short*     EhW   = (unsigned short*)(ws + EH_OFF);
  unsigned short*     ElW   = (unsigned short*)(ws + EL_OFF);

  hipMemsetAsync(ws, 0, SUMS_OFF + 32, stream);               // SX + counts + sums
  hipMemsetAsync(ws + NMIN_OFF, 0xFF, 524288, stream);        // nmin64 = +inf keys

  convert_kernel<<<(B_ROWS * (DDIM / 8) + KEMB * (DDIM / 8)) / 256, 256, 0, stream>>>(
      X, E, outU, EhW, ElW, sums);
  esq_kernel<<<KEMB, 64, 0, stream>>>(E, esq);
  gemm_argmin_kernel<<<(B_ROWS / BM) * 2, 256, 0, stream>>>(outU, EhW, ElW, esq, nm64);
  zq_kernel<<<B_ROWS / 4, 256, 0, stream>>>(nm64, E, out);
  hist_kernel<<<B_ROWS / 1024, 1024, 0, stream>>>(nm64, cnts);
  scan_kernel<<<1, 1024, 0, stream>>>(cnts, cur);
  scatter_kernel<<<B_ROWS / 1024, 1024, 0, stream>>>(nm64, cur, rows);
  sxsum_kernel<<<B_ROWS / 64, 256, 0, stream>>>(rows, nm64, X, SX);
  stencil_kernel<<<KEMB, 256, 0, stream>>>(E, SX, cnts, esq, sums, out);
  finalize_kernel<<<1, 1, 0, stream>>>(sums, out);
}

// Round 4
// 425.175 us; speedup vs baseline: 2.0601x; 1.2340x over previous
//
#include <hip/hip_runtime.h>

#define B_ROWS 65536
#define DDIM   256
#define KEMB   1024
#define LRC    0.05f
#define BM 128
#define BN 128
#define KC 32

typedef __attribute__((ext_vector_type(8))) short short8;
typedef __attribute__((ext_vector_type(4))) float f32x4;

// ---- workspace layout (bytes) ----
#define SX_OFF    0u            // 1 MB fp32 [K][D]
#define CNT_OFF   1048576u      // 4 KB int [K]
#define SUMS_OFF  1052672u      // 32 B, 4 doubles
#define ESQ_OFF   1052704u      // 4 KB fp32 [K]
#define CUR_OFF   1056800u      // 4 KB int [K]
#define NMIN_OFF  1060896u      // 512 KB u64 [B]
#define ROWS_OFF  1585184u      // 256 KB int [B]
#define EH_OFF    1847328u      // 512 KB bf16 [K][D]
#define EL_OFF    2371616u      // 512 KB

static __device__ __forceinline__ unsigned short f2bf(float f) {
  unsigned int u = __float_as_uint(f);
  u += 0x7fffu + ((u >> 16) & 1u);
  return (unsigned short)(u >> 16);
}
static __device__ __forceinline__ float bf2f(unsigned short h) {
  return __uint_as_float(((unsigned int)h) << 16);
}
static __device__ __forceinline__ int nmin_of(const unsigned long long* nm, int b) {
  return (int)(nm[b] & 0xffffffffull);
}
static __device__ __forceinline__ void glds16(const void* g, void* l) {
  __builtin_amdgcn_global_load_lds(
      (const __attribute__((address_space(1))) unsigned int*)g,
      (__attribute__((address_space(3))) unsigned int*)l, 16, 0, 0);
}

// ---------------- convert: X->hi/lo into out region; E->ws; esq; Sum|x|^2 ---------
__global__ __launch_bounds__(256) void convert_kernel(
    const float* __restrict__ X, const float* __restrict__ E,
    unsigned short* __restrict__ outU,
    unsigned short* __restrict__ Eh, unsigned short* __restrict__ El,
    float* __restrict__ esq, double* __restrict__ sums) {
  __shared__ float red[256];
  const size_t nX8 = (size_t)B_ROWS * DDIM / 8;
  size_t i = (size_t)blockIdx.x * 256 + threadIdx.x;
  const float* src;
  unsigned short *dh, *dl;
  bool isX = (i < nX8);
  if (isX) {
    size_t off = i * 8;
    src = X + off;
    dh = outU + (off >> 8) * 512 + (off & 255);
    dl = dh + 256;
  } else {
    size_t off = (i - nX8) * 8;
    src = E + off;
    dh = Eh + off;
    dl = El + off;
  }
  const float4 v0 = *(const float4*)src;
  const float4 v1 = *(const float4*)(src + 4);
  float f[8] = {v0.x, v0.y, v0.z, v0.w, v1.x, v1.y, v1.z, v1.w};
  unsigned short h[8], l[8];
  float part = 0.f;
#pragma unroll
  for (int j = 0; j < 8; ++j) {
    h[j] = f2bf(f[j]);
    l[j] = f2bf(f[j] - bf2f(h[j]));
    part += f[j] * f[j];
  }
  *(uint4*)dh = *(const uint4*)h;
  *(uint4*)dl = *(const uint4*)l;
  if (!isX) {
    float s = part;
    for (int off = 16; off > 0; off >>= 1) s += __shfl_down(s, off, 32);
    if ((threadIdx.x & 31) == 0) esq[(i - nX8) >> 5] = s;
  }
  red[threadIdx.x] = isX ? part : 0.f;
  __syncthreads();
  for (int s = 128; s > 0; s >>= 1) {
    if (threadIdx.x < s) red[threadIdx.x] += red[threadIdx.x + s];
    __syncthreads();
  }
  if (threadIdx.x == 0 && isX) atomicAdd(&sums[0], (double)red[0]);
}

// ---------------- A: MFMA dist-GEMM + argmin -> packed atomicMin ----------------
// LDS: 4 tiles x 512 chunks x 16B (Xh,Xl,Eh,El). chunk(row,q) = row*4 + (q^(row&3))
// -> fragment-read chunk ids uniform mod 8 across the wave = conflict-free b128.
__global__ __launch_bounds__(256, 4) void gemm_argmin_kernel(
    const unsigned short* __restrict__ XhlU,
    const unsigned short* __restrict__ EhW, const unsigned short* __restrict__ ElW,
    const float* __restrict__ esq, unsigned long long* __restrict__ nmin64) {
  __shared__ __align__(16) unsigned short sT[4][512][8];   // 32768 B

  const int tid  = threadIdx.x;
  const int lane = tid & 63, w = tid >> 6;
  const int lrow = lane & 15;
  const int qidx = lane >> 4;            // k-quarter 0..3
  const int rowbase = (w >> 1) * 64;
  const int colb    = (w & 1) * 64;
  // pair-swizzle: both nt-halves of a row-block share bid%8 -> same XCD L2
  const int bid = (int)blockIdx.x;
  const int g = bid >> 4, r = bid & 15;
  const int bm0 = (g * 8 + (r & 7)) * BM;
  const int ntbase = (r >> 3) * 4;

  float rbest[16];
  int   ridx[16];
#pragma unroll
  for (int i = 0; i < 16; ++i) { rbest[i] = 3.4e38f; ridx[i] = 0; }

  for (int ntl = 0; ntl < 4; ++ntl) {
    const int nt = ntbase + ntl;
    f32x4 acc[4][4];
#pragma unroll
    for (int i = 0; i < 4; ++i)
#pragma unroll
      for (int j = 0; j < 4; ++j) acc[i][j] = (f32x4){0.f, 0.f, 0.f, 0.f};

    const unsigned short* srcs[4];
    srcs[0] = XhlU + (size_t)bm0 * 512;
    srcs[1] = XhlU + (size_t)bm0 * 512 + 256;
    srcs[2] = EhW + (size_t)nt * BN * DDIM;
    srcs[3] = ElW + (size_t)nt * BN * DDIM;

    for (int kc = 0; kc < DDIM; kc += KC) {
      __syncthreads();
      // async stage: 8 glds/thread; lds dest = wave-uniform base + lane*16
#pragma unroll
      for (int j = 0; j < 8; ++j) {
        const int c    = j * 256 + tid;
        const int tile = c >> 9;                     // uniform per (j, wave)
        const int cc   = c & 511;
        const int row  = cc >> 2;
        const int q    = (cc & 3) ^ (row & 3);
        const int stride = (tile < 2) ? 512 : 256;
        const unsigned short* gp = srcs[tile] + (size_t)row * stride + kc + q * 8;
        char* lp = (char*)sT + (size_t)(j * 256 + w * 64) * 16;
        glds16(gp, lp);
      }
      __syncthreads();
#pragma unroll
      for (int p = 0; p < 3; ++p) {
        const int at = (p < 2) ? 0 : 1;
        const int bt = (p == 1) ? 3 : 2;
        short8 af[4], bfr[4];
#pragma unroll
        for (int t = 0; t < 4; ++t) {
          const int m  = rowbase + t * 16 + lrow;
          const int ca = (m << 2) | (qidx ^ (m & 3));
          af[t] = *(const short8*)&sT[at][ca][0];
          const int n  = colb + t * 16 + lrow;
          const int cb = (n << 2) | (qidx ^ (n & 3));
          bfr[t] = *(const short8*)&sT[bt][cb][0];
        }
#pragma unroll
        for (int tr = 0; tr < 4; ++tr)
#pragma unroll
          for (int tc = 0; tc < 4; ++tc)
            acc[tr][tc] = __builtin_amdgcn_mfma_f32_16x16x32_bf16(
                af[tr], bfr[tc], acc[tr][tc], 0, 0, 0);
      }
    }
#pragma unroll
    for (int tc = 0; tc < 4; ++tc) {
      const int col = nt * BN + colb + tc * 16 + lrow;
      const float eq = esq[col];
#pragma unroll
      for (int tr = 0; tr < 4; ++tr)
#pragma unroll
        for (int rr = 0; rr < 4; ++rr) {
          float d = eq - 2.0f * acc[tr][tc][rr];
          const int slot = tr * 4 + rr;
          if (d < rbest[slot]) { rbest[slot] = d; ridx[slot] = col; }
        }
    }
  }

  __syncthreads();  // reuse sT as reduction scratch
  float* cdd = (float*)&sT[0][0][0];      // [2][128]
  int*   cdi = (int*)(cdd + 256);         // [2][128]

#pragma unroll
  for (int slot = 0; slot < 16; ++slot) {
    float bd = rbest[slot];
    int   bi = ridx[slot];
#pragma unroll
    for (int off = 1; off < 16; off <<= 1) {
      float od = __shfl_xor(bd, off, 64);
      int   oi = __shfl_xor(bi, off, 64);
      if (od < bd || (od == bd && oi < bi)) { bd = od; bi = oi; }
    }
    if (lrow == 0) {
      const int row = rowbase + (slot >> 2) * 16 + (lane >> 4) * 4 + (slot & 3);
      cdd[(w & 1) * 128 + row] = bd;
      cdi[(w & 1) * 128 + row] = bi;
    }
  }
  __syncthreads();
  if (tid < BM) {
    float d0 = cdd[tid], d1 = cdd[128 + tid];
    int   i0 = cdi[tid], i1 = cdi[128 + tid];
    float bd = d0; int bi = i0;
    if (d1 < d0 || (d1 == d0 && i1 < i0)) { bd = d1; bi = i1; }
    unsigned int fb = __float_as_uint(bd);
    fb = (fb & 0x80000000u) ? ~fb : (fb | 0x80000000u);
    unsigned long long key = ((unsigned long long)fb << 32) | (unsigned int)bi;
    atomicMin(&nmin64[bm0 + tid], key);
  }
}

// ---------------- zq gather ----------------
__global__ __launch_bounds__(256) void zq_kernel(
    const unsigned long long* __restrict__ nm, const float* __restrict__ E,
    float* __restrict__ zq) {
  int row = blockIdx.x * 4 + (threadIdx.x >> 6);
  int lane = threadIdx.x & 63;
  int k = nmin_of(nm, row);
  const float4 v = *(const float4*)(E + (size_t)k * DDIM + lane * 4);
  *(float4*)(zq + (size_t)row * DDIM + lane * 4) = v;
}

// ---------------- hist ----------------
__global__ __launch_bounds__(1024) void hist_kernel(
    const unsigned long long* __restrict__ nm, int* __restrict__ counts) {
  __shared__ int h[KEMB];
  int tid = threadIdx.x;
  h[tid] = 0;
  __syncthreads();
  int k = nmin_of(nm, blockIdx.x * 1024 + tid);
  atomicAdd(&h[k], 1);
  __syncthreads();
  if (h[tid] > 0) atomicAdd(&counts[tid], h[tid]);
}

// ---------------- scan ----------------
__global__ __launch_bounds__(1024) void scan_kernel(
    const int* __restrict__ counts, int* __restrict__ cur) {
  __shared__ int tmp[KEMB];
  int tid = threadIdx.x;
  int v = counts[tid];
  tmp[tid] = v;
  __syncthreads();
  for (int off = 1; off < 1024; off <<= 1) {
    int u = (tid >= off) ? tmp[tid - off] : 0;
    __syncthreads();
    tmp[tid] += u;
    __syncthreads();
  }
  cur[tid] = tmp[tid] - v;
}

// ---------------- scatter: counting-sort row ids by k ----------------
__global__ __launch_bounds__(1024) void scatter_kernel(
    const unsigned long long* __restrict__ nm, int* __restrict__ cur,
    int* __restrict__ rows) {
  __shared__ int lcnt[KEMB], lbase[KEMB], lrank[KEMB];
  int tid = threadIdx.x;
  lcnt[tid] = 0; lrank[tid] = 0;
  __syncthreads();
  int b = blockIdx.x * 1024 + tid;
  int k = nmin_of(nm, b);
  atomicAdd(&lcnt[k], 1);
  __syncthreads();
  if (lcnt[tid] > 0) lbase[tid] = atomicAdd(&cur[tid], lcnt[tid]);
  __syncthreads();
  int r = atomicAdd(&lrank[k], 1);
  rows[lbase[k] + r] = b;
}

// ---------------- sxsum: segment-sum sorted chunks into SX ----------------
__global__ __launch_bounds__(256) void sxsum_kernel(
    const int* __restrict__ rows, const unsigned long long* __restrict__ nm,
    const float* __restrict__ X, float* __restrict__ SX) {
  __shared__ int sb[64], sk[64];
  int tid = threadIdx.x;
  int p0 = blockIdx.x * 64;
  if (tid < 64) sb[tid] = rows[p0 + tid];
  __syncthreads();
  if (tid < 64) sk[tid] = nmin_of(nm, sb[tid]);
  __syncthreads();
  float acc = 0.f;
  int kprev = sk[0];
  for (int i = 0; i < 64; ++i) {
    int k = sk[i];
    if (k != kprev) {
      atomicAdd(&SX[(size_t)kprev * DDIM + tid], acc);
      acc = 0.f;
      kprev = k;
    }
    acc += X[(size_t)sb[i] * DDIM + tid];
  }
  atomicAdd(&SX[(size_t)kprev * DDIM + tid], acc);
}

// ---------------- stencil: new_embeddings + loss partials ----------------
__global__ __launch_bounds__(256) void stencil_kernel(
    const float* __restrict__ E, const float* __restrict__ SX,
    const int* __restrict__ counts, const float* __restrict__ esq,
    double* __restrict__ sums, float* __restrict__ out) {
  __shared__ float redc[256], reds[256];
  int k = blockIdx.x, t = threadIdx.x;
  int kx = k >> 5, ky = k & 31;
  int j1 = (kx >= 1)  ? k - 32 : k;
  int j2 = (kx <= 30) ? k + 32 : k;
  int j3 = (ky >= 1)  ? k - 1  : k;
  int j4 = (ky <= 30) ? k + 1  : k;
  int fU = (kx < 31) ? k + 32 : k;
  int fD = (kx > 0)  ? k - 32 : k;
  int fL = (ky > 0)  ? k - 1  : k;
  int fR = (ky < 31) ? k + 1  : k;

  float e   = E[(size_t)k * DDIM + t];
  float sxk = SX[(size_t)k * DDIM + t];
  float Tk = sxk - (float)counts[k] * e;
  float T1 = SX[(size_t)j1 * DDIM + t] - (float)counts[j1] * E[(size_t)j1 * DDIM + t];
  float T2 = SX[(size_t)j2 * DDIM + t] - (float)counts[j2] * E[(size_t)j2 * DDIM + t];
  float T3 = SX[(size_t)j3 * DDIM + t] - (float)counts[j3] * E[(size_t)j3 * DDIM + t];
  float T4 = SX[(size_t)j4 * DDIM + t] - (float)counts[j4] * E[(size_t)j4 * DDIM + t];
  float v = e + LRC * Tk + 0.5f * LRC * (T1 + T2 + T3 + T4);
  out[(size_t)B_ROWS * DDIM + 2 + (size_t)k * DDIM + t] = v;

  float eU = E[(size_t)fU * DDIM + t], eD = E[(size_t)fD * DDIM + t];
  float eL = E[(size_t)fL * DDIM + t], eR = E[(size_t)fR * DDIM + t];
  float cp = -2.f * sxk * e;
  float sp = -2.f * sxk * (eU + eD + eL + eR);
  if (t == 0) {
    float ck = (float)counts[k];
    cp += ck * esq[k];
    sp += ck * (esq[fU] + esq[fD] + esq[fL] + esq[fR]);
  }
  redc[t] = cp; reds[t] = sp;
  __syncthreads();
  for (int s = 128; s > 0; s >>= 1) {
    if (t < s) { redc[t] += redc[t + s]; reds[t] += reds[t + s]; }
    __syncthreads();
  }
  if (t == 0) {
    atomicAdd(&sums[1], (double)redc[0]);
    atomicAdd(&sums[2], (double)reds[0]);
  }
}

// ---------------- finalize losses ----------------
__global__ void finalize_kernel(const double* __restrict__ sums,
                                float* __restrict__ out) {
  double xsq = sums[0];
  out[(size_t)B_ROWS * DDIM]     = (float)((xsq + sums[1]) / ((double)B_ROWS * DDIM));
  out[(size_t)B_ROWS * DDIM + 1] =
      (float)((4.0 * xsq + sums[2]) / ((double)B_ROWS * 4.0 * DDIM));
}

extern "C" void kernel_launch(void* const* d_in, const int* in_sizes, int n_in,
                              void* d_out, int out_size, void* d_ws, size_t ws_size,
                              hipStream_t stream) {
  const float* X = (const float*)d_in[0];
  const float* E = (const float*)d_in[1];
  float* out = (float*)d_out;
  unsigned short* outU = (unsigned short*)d_out;
  char* ws = (char*)d_ws;

  float*              SX    = (float*)(ws + SX_OFF);
  int*                cnts  = (int*)(ws + CNT_OFF);
  double*             sums  = (double*)(ws + SUMS_OFF);
  float*              esq   = (float*)(ws + ESQ_OFF);
  int*                cur   = (int*)(ws + CUR_OFF);
  unsigned long long* nm64  = (unsigned long long*)(ws + NMIN_OFF);
  int*                rows  = (int*)(ws + ROWS_OFF);
  unsigned short*     EhW   = (unsigned short*)(ws + EH_OFF);
  unsigned short*     ElW   = (unsigned short*)(ws + EL_OFF);

  hipMemsetAsync(ws, 0, SUMS_OFF + 32, stream);               // SX + counts + sums
  hipMemsetAsync(ws + NMIN_OFF, 0xFF, 524288, stream);        // nmin64 = +inf keys

  convert_kernel<<<(B_ROWS * (DDIM / 8) + KEMB * (DDIM / 8)) / 256, 256, 0, stream>>>(
      X, E, outU, EhW, ElW, esq, sums);
  gemm_argmin_kernel<<<(B_ROWS / BM) * 2, 256, 0, stream>>>(outU, EhW, ElW, esq, nm64);
  zq_kernel<<<B_ROWS / 4, 256, 0, stream>>>(nm64, E, out);
  hist_kernel<<<B_ROWS / 1024, 1024, 0, stream>>>(nm64, cnts);
  scan_kernel<<<1, 1024, 0, stream>>>(cnts, cur);
  scatter_kernel<<<B_ROWS / 1024, 1024, 0, stream>>>(nm64, cur, rows);
  sxsum_kernel<<<B_ROWS / 64, 256, 0, stream>>>(rows, nm64, X, SX);
  stencil_kernel<<<KEMB, 256, 0, stream>>>(E, SX, cnts, esq, sums, out);
  finalize_kernel<<<1, 1, 0, stream>>>(sums, out);
}

// Round 5
// 328.808 us; speedup vs baseline: 2.6638x; 1.2931x over previous
//
#include <hip/hip_runtime.h>

#define B_ROWS 65536
#define DDIM   256
#define KEMB   1024
#define LRC    0.05f
#define BM 128
#define BN 128
#define KC 32

typedef __attribute__((ext_vector_type(8))) _Float16 half8;
typedef __attribute__((ext_vector_type(4))) float f32x4;

// ---- workspace layout (bytes) ----
#define SX_OFF    0u            // 1 MB fp32 [K][D]
#define CNT_OFF   1048576u      // 4 KB int [K]
#define SUMS_OFF  1052672u      // 640 B: 80 doubles ([1]=commit,[2]=som,[8..71]=xsq slots)
#define ESQ_OFF   1053312u      // 4 KB fp32 [K]
#define CUR_OFF   1057408u      // 4 KB int [K]
#define NMIN_OFF  1061504u      // 512 KB u64 [B]
#define ROWS_OFF  1585792u      // 256 KB int [B]
#define EH_OFF    1847936u      // 512 KB f16 [K][D]

static __device__ __forceinline__ unsigned short f2h(float f) {
  _Float16 h = (_Float16)f;
  return *(unsigned short*)&h;
}
static __device__ __forceinline__ float h2f(unsigned short u) {
  _Float16 h = *(_Float16*)&u;
  return (float)h;
}
static __device__ __forceinline__ int nmin_of(const unsigned long long* nm, int b) {
  return (int)(nm[b] & 0xffffffffull);
}
static __device__ __forceinline__ void glds16(const void* g, void* l) {
  __builtin_amdgcn_global_load_lds(
      (const __attribute__((address_space(1))) unsigned int*)g,
      (__attribute__((address_space(3))) unsigned int*)l, 16, 0, 0);
}

// ---------------- convert: X->hi/lo f16 into out region; E->Eh f16; esq; |x|^2 ----
__global__ __launch_bounds__(256) void convert_kernel(
    const float* __restrict__ X, const float* __restrict__ E,
    unsigned short* __restrict__ outU, unsigned short* __restrict__ Eh,
    float* __restrict__ esq, double* __restrict__ sums) {
  __shared__ float red[256];
  const size_t nX8 = (size_t)B_ROWS * DDIM / 8;
  size_t i = (size_t)blockIdx.x * 256 + threadIdx.x;
  bool isX = (i < nX8);
  const float* src;
  unsigned short *dh, *dl = nullptr;
  if (isX) {
    size_t off = i * 8;
    src = X + off;
    dh = outU + (off >> 8) * 512 + (off & 255);
    dl = dh + 256;
  } else {
    size_t off = (i - nX8) * 8;
    src = E + off;
    dh = Eh + off;
  }
  const float4 v0 = *(const float4*)src;
  const float4 v1 = *(const float4*)(src + 4);
  float f[8] = {v0.x, v0.y, v0.z, v0.w, v1.x, v1.y, v1.z, v1.w};
  unsigned short h[8], l[8];
  float part = 0.f;
#pragma unroll
  for (int j = 0; j < 8; ++j) {
    h[j] = f2h(f[j]);
    l[j] = f2h(f[j] - h2f(h[j]));
    part += f[j] * f[j];
  }
  *(uint4*)dh = *(const uint4*)h;
  if (isX) *(uint4*)dl = *(const uint4*)l;
  if (!isX) {
    float s = part;
    for (int off = 16; off > 0; off >>= 1) s += __shfl_down(s, off, 32);
    if ((threadIdx.x & 31) == 0) esq[(i - nX8) >> 5] = s;
  }
  red[threadIdx.x] = isX ? part : 0.f;
  __syncthreads();
  for (int s = 128; s > 0; s >>= 1) {
    if (threadIdx.x < s) red[threadIdx.x] += red[threadIdx.x + s];
    __syncthreads();
  }
  // 64-slot spread: avoids single-address f64 atomic serialization
  if (threadIdx.x == 0 && isX)
    atomicAdd(&sums[8 + ((int)blockIdx.x & 63)], (double)red[0]);
}

// ---------------- A: MFMA f16 2-pass dist-GEMM + argmin -> packed atomicMin -------
// dist = esq_exact[k] - 2*(xh+xl)·eh.  LDS: 3 tiles x 512 chunks x 16B.
// chunk(row,slot): holds k-quarter q = slot ^ ((row>>1)&3)
//   -> read chunk ca = 4m + (qidx ^ ((m>>1)&3)); ca mod 8 uniform 2-way = free.
__global__ __launch_bounds__(256, 4) void gemm_argmin_kernel(
    const unsigned short* __restrict__ XhlU, const unsigned short* __restrict__ EhW,
    const float* __restrict__ esq, unsigned long long* __restrict__ nmin64) {
  __shared__ __align__(16) unsigned short sT[3][512][8];   // 24576 B

  const int tid  = threadIdx.x;
  const int lane = tid & 63, w = tid >> 6;
  const int lrow = lane & 15;
  const int qidx = lane >> 4;            // k-quarter 0..3
  const int rowbase = (w >> 1) * 64;
  const int colb    = (w & 1) * 64;
  // pair-swizzle: both nt-halves of a row-block share bid%8 -> same XCD L2
  const int bid = (int)blockIdx.x;
  const int g = bid >> 4, r = bid & 15;
  const int bm0 = (g * 8 + (r & 7)) * BM;
  const int ntbase = (r >> 3) * 4;

  float rbest[16];
  int   ridx[16];
#pragma unroll
  for (int i = 0; i < 16; ++i) { rbest[i] = 3.4e38f; ridx[i] = 0; }

  for (int ntl = 0; ntl < 4; ++ntl) {
    const int nt = ntbase + ntl;
    f32x4 acc[4][4];
#pragma unroll
    for (int i = 0; i < 4; ++i)
#pragma unroll
      for (int j = 0; j < 4; ++j) acc[i][j] = (f32x4){0.f, 0.f, 0.f, 0.f};

    const unsigned short* srcs[3];
    srcs[0] = XhlU + (size_t)bm0 * 512;          // X hi (row stride 512)
    srcs[1] = XhlU + (size_t)bm0 * 512 + 256;    // X lo
    srcs[2] = EhW + (size_t)nt * BN * DDIM;      // E hi (row stride 256)

    for (int kc = 0; kc < DDIM; kc += KC) {
      __syncthreads();
      // async stage: 6 glds16/thread; lds dest = wave-uniform base + lane*16
#pragma unroll
      for (int j = 0; j < 6; ++j) {
        const int c    = j * 256 + tid;
        const int tile = c >> 9;                  // uniform per (j, wave)
        const int cc   = c & 511;
        const int row  = cc >> 2;
        const int q    = (cc & 3) ^ ((row >> 1) & 3);
        const int stride = (tile < 2) ? 512 : 256;
        const unsigned short* gp = srcs[tile] + (size_t)row * stride + kc + q * 8;
        char* lp = (char*)sT + (size_t)c * 16;
        glds16(gp, lp);
      }
      __syncthreads();
      half8 bfr[4], af0[4], af1[4];
#pragma unroll
      for (int t = 0; t < 4; ++t) {
        const int m  = rowbase + t * 16 + lrow;
        const int sa = qidx ^ ((m >> 1) & 3);
        af0[t] = *(const half8*)&sT[0][(m << 2) | sa][0];
        af1[t] = *(const half8*)&sT[1][(m << 2) | sa][0];
        const int n  = colb + t * 16 + lrow;
        const int sb = qidx ^ ((n >> 1) & 3);
        bfr[t] = *(const half8*)&sT[2][(n << 2) | sb][0];
      }
#pragma unroll
      for (int tr = 0; tr < 4; ++tr)
#pragma unroll
        for (int tc = 0; tc < 4; ++tc)
          acc[tr][tc] = __builtin_amdgcn_mfma_f32_16x16x32_f16(
              af0[tr], bfr[tc], acc[tr][tc], 0, 0, 0);
#pragma unroll
      for (int tr = 0; tr < 4; ++tr)
#pragma unroll
        for (int tc = 0; tc < 4; ++tc)
          acc[tr][tc] = __builtin_amdgcn_mfma_f32_16x16x32_f16(
              af1[tr], bfr[tc], acc[tr][tc], 0, 0, 0);
    }
#pragma unroll
    for (int tc = 0; tc < 4; ++tc) {
      const int col = nt * BN + colb + tc * 16 + lrow;
      const float eq = esq[col];
#pragma unroll
      for (int tr = 0; tr < 4; ++tr)
#pragma unroll
        for (int rr = 0; rr < 4; ++rr) {
          float d = eq - 2.0f * acc[tr][tc][rr];
          const int slot = tr * 4 + rr;
          if (d < rbest[slot]) { rbest[slot] = d; ridx[slot] = col; }
        }
    }
  }

  __syncthreads();  // reuse sT as reduction scratch
  float* cdd = (float*)&sT[0][0][0];      // [2][128]
  int*   cdi = (int*)(cdd + 256);         // [2][128]

#pragma unroll
  for (int slot = 0; slot < 16; ++slot) {
    float bd = rbest[slot];
    int   bi = ridx[slot];
#pragma unroll
    for (int off = 1; off < 16; off <<= 1) {
      float od = __shfl_xor(bd, off, 64);
      int   oi = __shfl_xor(bi, off, 64);
      if (od < bd || (od == bd && oi < bi)) { bd = od; bi = oi; }
    }
    if (lrow == 0) {
      const int row = rowbase + (slot >> 2) * 16 + (lane >> 4) * 4 + (slot & 3);
      cdd[(w & 1) * 128 + row] = bd;
      cdi[(w & 1) * 128 + row] = bi;
    }
  }
  __syncthreads();
  if (tid < BM) {
    float d0 = cdd[tid], d1 = cdd[128 + tid];
    int   i0 = cdi[tid], i1 = cdi[128 + tid];
    float bd = d0; int bi = i0;
    if (d1 < d0 || (d1 == d0 && i1 < i0)) { bd = d1; bi = i1; }
    unsigned int fb = __float_as_uint(bd);
    fb = (fb & 0x80000000u) ? ~fb : (fb | 0x80000000u);
    unsigned long long key = ((unsigned long long)fb << 32) | (unsigned int)bi;
    atomicMin(&nmin64[bm0 + tid], key);
  }
}

// ---------------- zq gather ----------------
__global__ __launch_bounds__(256) void zq_kernel(
    const unsigned long long* __restrict__ nm, const float* __restrict__ E,
    float* __restrict__ zq) {
  int row = blockIdx.x * 4 + (threadIdx.x >> 6);
  int lane = threadIdx.x & 63;
  int k = nmin_of(nm, row);
  const float4 v = *(const float4*)(E + (size_t)k * DDIM + lane * 4);
  *(float4*)(zq + (size_t)row * DDIM + lane * 4) = v;
}

// ---------------- hist ----------------
__global__ __launch_bounds__(1024) void hist_kernel(
    const unsigned long long* __restrict__ nm, int* __restrict__ counts) {
  __shared__ int h[KEMB];
  int tid = threadIdx.x;
  h[tid] = 0;
  __syncthreads();
  int k = nmin_of(nm, blockIdx.x * 1024 + tid);
  atomicAdd(&h[k], 1);
  __syncthreads();
  if (h[tid] > 0) atomicAdd(&counts[tid], h[tid]);
}

// ---------------- scan ----------------
__global__ __launch_bounds__(1024) void scan_kernel(
    const int* __restrict__ counts, int* __restrict__ cur) {
  __shared__ int tmp[KEMB];
  int tid = threadIdx.x;
  int v = counts[tid];
  tmp[tid] = v;
  __syncthreads();
  for (int off = 1; off < 1024; off <<= 1) {
    int u = (tid >= off) ? tmp[tid - off] : 0;
    __syncthreads();
    tmp[tid] += u;
    __syncthreads();
  }
  cur[tid] = tmp[tid] - v;
}

// ---------------- scatter: counting-sort row ids by k ----------------
__global__ __launch_bounds__(1024) void scatter_kernel(
    const unsigned long long* __restrict__ nm, int* __restrict__ cur,
    int* __restrict__ rows) {
  __shared__ int lcnt[KEMB], lbase[KEMB], lrank[KEMB];
  int tid = threadIdx.x;
  lcnt[tid] = 0; lrank[tid] = 0;
  __syncthreads();
  int b = blockIdx.x * 1024 + tid;
  int k = nmin_of(nm, b);
  atomicAdd(&lcnt[k], 1);
  __syncthreads();
  if (lcnt[tid] > 0) lbase[tid] = atomicAdd(&cur[tid], lcnt[tid]);
  __syncthreads();
  int r = atomicAdd(&lrank[k], 1);
  rows[lbase[k] + r] = b;
}

// ---------------- sxsum: segment-sum sorted chunks into SX ----------------
__global__ __launch_bounds__(256) void sxsum_kernel(
    const int* __restrict__ rows, const unsigned long long* __restrict__ nm,
    const float* __restrict__ X, float* __restrict__ SX) {
  __shared__ int sb[64], sk[64];
  int tid = threadIdx.x;
  int p0 = blockIdx.x * 64;
  if (tid < 64) sb[tid] = rows[p0 + tid];
  __syncthreads();
  if (tid < 64) sk[tid] = nmin_of(nm, sb[tid]);
  __syncthreads();
  float acc = 0.f;
  int kprev = sk[0];
  for (int i = 0; i < 64; ++i) {
    int k = sk[i];
    if (k != kprev) {
      atomicAdd(&SX[(size_t)kprev * DDIM + tid], acc);
      acc = 0.f;
      kprev = k;
    }
    acc += X[(size_t)sb[i] * DDIM + tid];
  }
  atomicAdd(&SX[(size_t)kprev * DDIM + tid], acc);
}

// ---------------- stencil: new_embeddings + loss partials ----------------
__global__ __launch_bounds__(256) void stencil_kernel(
    const float* __restrict__ E, const float* __restrict__ SX,
    const int* __restrict__ counts, const float* __restrict__ esq,
    double* __restrict__ sums, float* __restrict__ out) {
  __shared__ float redc[256], reds[256];
  int k = blockIdx.x, t = threadIdx.x;
  int kx = k >> 5, ky = k & 31;
  int j1 = (kx >= 1)  ? k - 32 : k;
  int j2 = (kx <= 30) ? k + 32 : k;
  int j3 = (ky >= 1)  ? k - 1  : k;
  int j4 = (ky <= 30) ? k + 1  : k;
  int fU = (kx < 31) ? k + 32 : k;
  int fD = (kx > 0)  ? k - 32 : k;
  int fL = (ky > 0)  ? k - 1  : k;
  int fR = (ky < 31) ? k + 1  : k;

  float e   = E[(size_t)k * DDIM + t];
  float sxk = SX[(size_t)k * DDIM + t];
  float Tk = sxk - (float)counts[k] * e;
  float T1 = SX[(size_t)j1 * DDIM + t] - (float)counts[j1] * E[(size_t)j1 * DDIM + t];
  float T2 = SX[(size_t)j2 * DDIM + t] - (float)counts[j2] * E[(size_t)j2 * DDIM + t];
  float T3 = SX[(size_t)j3 * DDIM + t] - (float)counts[j3] * E[(size_t)j3 * DDIM + t];
  float T4 = SX[(size_t)j4 * DDIM + t] - (float)counts[j4] * E[(size_t)j4 * DDIM + t];
  float v = e + LRC * Tk + 0.5f * LRC * (T1 + T2 + T3 + T4);
  out[(size_t)B_ROWS * DDIM + 2 + (size_t)k * DDIM + t] = v;

  float eU = E[(size_t)fU * DDIM + t], eD = E[(size_t)fD * DDIM + t];
  float eL = E[(size_t)fL * DDIM + t], eR = E[(size_t)fR * DDIM + t];
  float cp = -2.f * sxk * e;
  float sp = -2.f * sxk * (eU + eD + eL + eR);
  if (t == 0) {
    float ck = (float)counts[k];
    cp += ck * esq[k];
    sp += ck * (esq[fU] + esq[fD] + esq[fL] + esq[fR]);
  }
  redc[t] = cp; reds[t] = sp;
  __syncthreads();
  for (int s = 128; s > 0; s >>= 1) {
    if (t < s) { redc[t] += redc[t + s]; reds[t] += reds[t + s]; }
    __syncthreads();
  }
  if (t == 0) {
    atomicAdd(&sums[1], (double)redc[0]);
    atomicAdd(&sums[2], (double)reds[0]);
  }
}

// ---------------- finalize losses ----------------
__global__ void finalize_kernel(const double* __restrict__ sums,
                                float* __restrict__ out) {
  double xsq = 0.0;
  for (int s = 0; s < 64; ++s) xsq += sums[8 + s];
  out[(size_t)B_ROWS * DDIM]     = (float)((xsq + sums[1]) / ((double)B_ROWS * DDIM));
  out[(size_t)B_ROWS * DDIM + 1] =
      (float)((4.0 * xsq + sums[2]) / ((double)B_ROWS * 4.0 * DDIM));
}

extern "C" void kernel_launch(void* const* d_in, const int* in_sizes, int n_in,
                              void* d_out, int out_size, void* d_ws, size_t ws_size,
                              hipStream_t stream) {
  const float* X = (const float*)d_in[0];
  const float* E = (const float*)d_in[1];
  float* out = (float*)d_out;
  unsigned short* outU = (unsigned short*)d_out;
  char* ws = (char*)d_ws;

  float*              SX    = (float*)(ws + SX_OFF);
  int*                cnts  = (int*)(ws + CNT_OFF);
  double*             sums  = (double*)(ws + SUMS_OFF);
  float*              esq   = (float*)(ws + ESQ_OFF);
  int*                cur   = (int*)(ws + CUR_OFF);
  unsigned long long* nm64  = (unsigned long long*)(ws + NMIN_OFF);
  int*                rows  = (int*)(ws + ROWS_OFF);
  unsigned short*     EhW   = (unsigned short*)(ws + EH_OFF);

  hipMemsetAsync(ws, 0, ESQ_OFF, stream);                     // SX + counts + sums
  hipMemsetAsync(ws + NMIN_OFF, 0xFF, 524288, stream);        // nmin64 = +inf keys

  convert_kernel<<<(B_ROWS * (DDIM / 8) + KEMB * (DDIM / 8)) / 256, 256, 0, stream>>>(
      X, E, outU, EhW, esq, sums);
  gemm_argmin_kernel<<<(B_ROWS / BM) * 2, 256, 0, stream>>>(outU, EhW, esq, nm64);
  zq_kernel<<<B_ROWS / 4, 256, 0, stream>>>(nm64, E, out);
  hist_kernel<<<B_ROWS / 1024, 1024, 0, stream>>>(nm64, cnts);
  scan_kernel<<<1, 1024, 0, stream>>>(cnts, cur);
  scatter_kernel<<<B_ROWS / 1024, 1024, 0, stream>>>(nm64, cur, rows);
  sxsum_kernel<<<B_ROWS / 64, 256, 0, stream>>>(rows, nm64, X, SX);
  stencil_kernel<<<KEMB, 256, 0, stream>>>(E, SX, cnts, esq, sums, out);
  finalize_kernel<<<1, 1, 0, stream>>>(sums, out);
}